// Round 1
// baseline (153.834 us; speedup 1.0000x reference)
//
#include <hip/hip_runtime.h>
#include <math.h>

#define ALPHA 0.2f

// ---------------------------------------------------------------------------
// Kernel A: per-batch GEMM  C[b][k][e2] = sum_w x[b][w][k] * W2[e2][w]
//   e2 <  512 : L'[b][k][e2]     = C + b_lin[e2]      (layout (8,256,512), e contiguous)
//   e2 >= 512 : R_t[b][e2-512][k] = C                 (layout (8,512,256), j contiguous)
// 64x64 output tile, BK=16, 256 threads, 4x4 per thread.
// ---------------------------------------------------------------------------
__global__ __launch_bounds__(256) void gemm_kernel(
    const float* __restrict__ x,      // (8,256,256)  x[b][w][k]
    const float* __restrict__ W,      // (512,512)    W[e][c]
    const float* __restrict__ b_lin,  // (512)
    float* __restrict__ Lp,           // (8,256,512)
    float* __restrict__ Rt)           // (8,512,256)
{
    const int b  = blockIdx.z;
    const int k0 = blockIdx.y * 64;
    const int e0 = blockIdx.x * 64;           // e2 tile base, 0..960
    const bool is_right = (e0 >= 512);

    __shared__ float As[16][64];              // [w][k]
    __shared__ float Bs[16][68];              // [w][e] (+4 pad, keeps 16B align)

    const int tid = threadIdx.x;
    const int tx  = tid & 15;                 // e direction
    const int ty  = tid >> 4;                 // k direction

    const float* xb = x + b * 65536;
    const int wrow_off = is_right ? (e0 - 512) : e0;  // W row base for this tile
    const int wcol_off = is_right ? 256 : 0;          // W col base

    float acc[4][4];
    #pragma unroll
    for (int i = 0; i < 4; i++)
        #pragma unroll
        for (int j = 0; j < 4; j++) acc[i][j] = 0.f;

    for (int w0 = 0; w0 < 256; w0 += 16) {
        // A tile: As[w][k] = x[b][w0+w][k0+k]; 16x64 floats, float4 coalesced
        {
            const int w  = tid >> 4;          // 0..15
            const int k4 = (tid & 15) * 4;    // 0..60
            const float4 v = *(const float4*)(xb + (w0 + w) * 256 + k0 + k4);
            *(float4*)&As[w][k4] = v;
        }
        // B tile: Bs[w][e] = W[wrow_off+e][wcol_off+w0+w]; transpose on store
        {
            const int e  = tid >> 2;          // 0..63
            const int w4 = (tid & 3) * 4;     // 0..12
            const float4 v = *(const float4*)(W + (wrow_off + e) * 512 + wcol_off + w0 + w4);
            Bs[w4 + 0][e] = v.x;
            Bs[w4 + 1][e] = v.y;
            Bs[w4 + 2][e] = v.z;
            Bs[w4 + 3][e] = v.w;
        }
        __syncthreads();
        #pragma unroll
        for (int w = 0; w < 16; w++) {
            float a4[4], b4[4];
            *(float4*)a4 = *(const float4*)&As[w][ty * 4];
            *(float4*)b4 = *(const float4*)&Bs[w][tx * 4];
            #pragma unroll
            for (int i = 0; i < 4; i++)
                #pragma unroll
                for (int j = 0; j < 4; j++)
                    acc[i][j] += a4[i] * b4[j];
        }
        __syncthreads();
    }

    if (!is_right) {
        float bl[4];
        *(float4*)bl = *(const float4*)(b_lin + e0 + tx * 4);
        #pragma unroll
        for (int i = 0; i < 4; i++) {
            float4 o;
            o.x = acc[i][0] + bl[0];
            o.y = acc[i][1] + bl[1];
            o.z = acc[i][2] + bl[2];
            o.w = acc[i][3] + bl[3];
            *(float4*)(Lp + b * 131072 + (k0 + ty * 4 + i) * 512 + e0 + tx * 4) = o;
        }
    } else {
        #pragma unroll
        for (int j = 0; j < 4; j++) {
            float4 o;
            o.x = acc[0][j];
            o.y = acc[1][j];
            o.z = acc[2][j];
            o.w = acc[3][j];
            *(float4*)(Rt + b * 131072 + (e0 - 512 + tx * 4 + j) * 256 + k0 + ty * 4) = o;
        }
    }
}

// ---------------------------------------------------------------------------
// Kernel B: per (b, 4-row i-tile): scores + softmax + attn@v + sigmoid + T-store
// 256 threads: thread = j for score phase, thread = w' for matvec phase.
// ---------------------------------------------------------------------------
__global__ __launch_bounds__(256) void attn_kernel(
    const float* __restrict__ x,      // (8,256,256)  x[b][w][j]
    const float* __restrict__ Lp,     // (8,256,512)  b_lin folded
    const float* __restrict__ Rt,     // (8,512,256)
    const float* __restrict__ a,      // (512)
    const float* __restrict__ bias,   // (256,256)
    float* __restrict__ out)          // (8,256,256)  out[b][w][i]
{
    const int b   = blockIdx.x >> 6;
    const int i0  = (blockIdx.x & 63) * 4;
    const int tid = threadIdx.x;

    __shared__ float Ls[4][512];
    __shared__ float a_s[512];
    __shared__ float at[4][256];

    // stage L' rows (coalesced) and a into LDS
    const float* LpB = Lp + b * 131072 + i0 * 512;
    #pragma unroll
    for (int idx = tid; idx < 2048; idx += 256)
        Ls[idx >> 9][idx & 511] = LpB[idx];
    #pragma unroll
    for (int idx = tid; idx < 512; idx += 256)
        a_s[idx] = a[idx];
    __syncthreads();

    // ---- score phase: thread = j ----
    const float* RtB = Rt + b * 131072 + tid;   // stride 256 floats per e
    float acc[4] = {0.f, 0.f, 0.f, 0.f};
    for (int e = 0; e < 512; e += 4) {
        float4 rv;
        rv.x = RtB[(e + 0) * 256];
        rv.y = RtB[(e + 1) * 256];
        rv.z = RtB[(e + 2) * 256];
        rv.w = RtB[(e + 3) * 256];
        const float4 av = *(const float4*)&a_s[e];
        #pragma unroll
        for (int i = 0; i < 4; i++) {
            const float4 lv = *(const float4*)&Ls[i][e];
            float p;
            p = lv.x + rv.x; acc[i] += av.x * fmaxf(p, ALPHA * p);
            p = lv.y + rv.y; acc[i] += av.y * fmaxf(p, ALPHA * p);
            p = lv.z + rv.z; acc[i] += av.z * fmaxf(p, ALPHA * p);
            p = lv.w + rv.w; acc[i] += av.w * fmaxf(p, ALPHA * p);
        }
    }
    #pragma unroll
    for (int i = 0; i < 4; i++) {
        acc[i] += bias[(i0 + i) * 256 + tid];
        at[i][tid] = acc[i];
    }
    __syncthreads();

    // ---- softmax: wave w handles row i=w (4 waves, 256 j each) ----
    {
        const int i    = tid >> 6;
        const int lane = tid & 63;
        float v[4];
        float m = -1e30f;
        #pragma unroll
        for (int u = 0; u < 4; u++) {
            v[u] = at[i][lane + 64 * u];
            m = fmaxf(m, v[u]);
        }
        #pragma unroll
        for (int off = 32; off; off >>= 1) m = fmaxf(m, __shfl_xor(m, off));
        float s = 0.f;
        #pragma unroll
        for (int u = 0; u < 4; u++) {
            v[u] = __expf(v[u] - m);
            s += v[u];
        }
        #pragma unroll
        for (int off = 32; off; off >>= 1) s += __shfl_xor(s, off);
        const float inv = 1.f / s;
        #pragma unroll
        for (int u = 0; u < 4; u++) at[i][lane + 64 * u] = v[u] * inv;
    }
    __syncthreads();

    // ---- matvec phase: thread = w'; h[i] = sum_j attn[i][j] * x[b][w'][j] ----
    const float* xrow = x + b * 65536 + tid * 256;
    float h[4] = {0.f, 0.f, 0.f, 0.f};
    for (int j = 0; j < 256; j += 4) {
        const float4 xv = *(const float4*)(xrow + j);
        #pragma unroll
        for (int i = 0; i < 4; i++) {
            const float4 pv = *(const float4*)&at[i][j];
            h[i] += pv.x * xv.x + pv.y * xv.y + pv.z * xv.z + pv.w * xv.w;
        }
    }
    float4 o;
    o.x = 1.f / (1.f + __expf(-h[0]));
    o.y = 1.f / (1.f + __expf(-h[1]));
    o.z = 1.f / (1.f + __expf(-h[2]));
    o.w = 1.f / (1.f + __expf(-h[3]));
    *(float4*)(out + b * 65536 + tid * 256 + i0) = o;
}

extern "C" void kernel_launch(void* const* d_in, const int* in_sizes, int n_in,
                              void* d_out, int out_size, void* d_ws, size_t ws_size,
                              hipStream_t stream) {
    const float* x     = (const float*)d_in[0];
    const float* W     = (const float*)d_in[1];
    const float* b_lin = (const float*)d_in[2];
    const float* a     = (const float*)d_in[3];
    const float* bias  = (const float*)d_in[4];
    float* out = (float*)d_out;

    float* Lp = (float*)d_ws;            // 8*256*512 floats = 4 MB
    float* Rt = Lp + 8 * 256 * 512;      // 8*512*256 floats = 4 MB

    dim3 gridA(16, 4, 8);                // e2-tiles, k-tiles, batch
    gemm_kernel<<<gridA, 256, 0, stream>>>(x, W, b_lin, Lp, Rt);
    attn_kernel<<<512, 256, 0, stream>>>(x, Lp, Rt, a, bias, out);
}

// Round 2
// 129.410 us; speedup vs baseline: 1.1887x; 1.1887x over previous
//
#include <hip/hip_runtime.h>
#include <math.h>

#define ALPHA 0.2f

typedef float f32x4 __attribute__((ext_vector_type(4)));
typedef __bf16 bf16x8 __attribute__((ext_vector_type(8)));
typedef unsigned short u16x8 __attribute__((ext_vector_type(8)));

__device__ __forceinline__ unsigned short f2bf(float f) {
    union { float f; unsigned int u; } v; v.f = f;
    unsigned int u = v.u;
    return (unsigned short)((u + 0x7fffu + ((u >> 16) & 1u)) >> 16);  // RNE
}
__device__ __forceinline__ float bf2f(unsigned int bits) {
    union { unsigned int u; float f; } v; v.u = bits << 16;
    return v.f;
}

// ---------------------------------------------------------------------------
// Kernel 0: convert/pack.
//  blocks [0,128):  xT_bf[b][k][w] = bf16(x[b][w][k])       (8,256,256)
//  blocks [128,256): Wb[e2][w] = bf16(e2<512 ? W[e2][w] : W[e2-512][256+w])
// ---------------------------------------------------------------------------
__global__ __launch_bounds__(256) void convert_kernel(
    const float* __restrict__ x, const float* __restrict__ W,
    unsigned short* __restrict__ xT, unsigned short* __restrict__ Wb)
{
    const int tid = threadIdx.x;
    if (blockIdx.x < 128) {
        const int b  = blockIdx.x >> 4;
        const int tt = blockIdx.x & 15;
        const int k0 = (tt >> 2) * 64;
        const int w0 = (tt & 3) * 64;
        __shared__ float Td[64][68];   // Td[k][w]
        const int wl = tid >> 4;       // 0..15
        const int kg = tid & 15;       // 0..15
        #pragma unroll
        for (int p = 0; p < 4; p++) {
            const int w = wl + 16 * p;
            const float4 v = *(const float4*)(x + b * 65536 + (w0 + w) * 256 + k0 + kg * 4);
            Td[kg * 4 + 0][w] = v.x;
            Td[kg * 4 + 1][w] = v.y;
            Td[kg * 4 + 2][w] = v.z;
            Td[kg * 4 + 3][w] = v.w;
        }
        __syncthreads();
        const int c8 = (tid & 7) * 8;
        #pragma unroll
        for (int p = 0; p < 2; p++) {
            const int rk = (tid >> 3) + 32 * p;
            u16x8 o;
            #pragma unroll
            for (int j = 0; j < 8; j++) o[j] = f2bf(Td[rk][c8 + j]);
            *(u16x8*)(xT + b * 65536 + (k0 + rk) * 256 + w0 + c8) = o;
        }
    } else {
        const int base = (blockIdx.x - 128) * 2048 + tid * 8;
        const int e2 = base >> 8;
        const int w8 = base & 255;
        const float* src = (e2 < 512) ? (W + e2 * 512 + w8)
                                      : (W + (e2 - 512) * 512 + 256 + w8);
        const float4 v0 = *(const float4*)(src);
        const float4 v1 = *(const float4*)(src + 4);
        u16x8 o;
        o[0] = f2bf(v0.x); o[1] = f2bf(v0.y); o[2] = f2bf(v0.z); o[3] = f2bf(v0.w);
        o[4] = f2bf(v1.x); o[5] = f2bf(v1.y); o[6] = f2bf(v1.z); o[7] = f2bf(v1.w);
        *(u16x8*)(Wb + e2 * 256 + w8) = o;
    }
}

// ---------------------------------------------------------------------------
// Kernel 1: MFMA bf16 GEMM, C[m][n] = sum_k A[m][k]*B[n][k], K=256.
//  left  (tiles 0..31):  A=xT[b] (M=256,k), B=Wb[0:512] (N=512,e)
//        -> Lp[b][k][e] = C + b_lin[e]   (fp32)
//  right (tiles 32..63): A=Wb[512:1024] (M=512,e), B=xT[b] (N=256,j)
//        -> Rt[b][e][j] = bf16(C)        (coalesced over j)
// 64x64 tile / block, 4 waves in 2x2, each wave 32x32 via 2x2 mfma_16x16x32.
// ---------------------------------------------------------------------------
__global__ __launch_bounds__(256) void mfma_gemm_kernel(
    const unsigned short* __restrict__ xT, const unsigned short* __restrict__ Wb,
    const float* __restrict__ b_lin,
    float* __restrict__ Lp, unsigned short* __restrict__ Rt)
{
    const int b = blockIdx.y;
    const int t = blockIdx.x;
    const bool left = (t < 32);
    const unsigned short *A, *B;
    int m0, n0;
    if (left) {
        m0 = (t >> 3) * 64; n0 = (t & 7) * 64;
        A = xT + b * 65536; B = Wb;
    } else {
        const int tt = t - 32;
        m0 = (tt >> 2) * 64; n0 = (tt & 3) * 64;
        A = Wb + 512 * 256; B = xT + b * 65536;
    }

    __shared__ unsigned short As[64][72];
    __shared__ unsigned short Bs[64][72];

    const int tid  = threadIdx.x;
    const int wv   = tid >> 6;
    const int lane = tid & 63;
    const int wy = wv >> 1, wx = wv & 1;
    const int lr = lane & 15;
    const int lk = lane >> 4;

    f32x4 acc[2][2];
    #pragma unroll
    for (int i = 0; i < 2; i++)
        #pragma unroll
        for (int j = 0; j < 2; j++) acc[i][j] = (f32x4){0.f, 0.f, 0.f, 0.f};

    const int sr = tid >> 3;           // 0..31
    const int sc = (tid & 7) * 8;      // 0..56

    for (int k0 = 0; k0 < 256; k0 += 64) {
        *(u16x8*)&As[sr][sc]      = *(const u16x8*)(A + (m0 + sr) * 256 + k0 + sc);
        *(u16x8*)&As[sr + 32][sc] = *(const u16x8*)(A + (m0 + sr + 32) * 256 + k0 + sc);
        *(u16x8*)&Bs[sr][sc]      = *(const u16x8*)(B + (n0 + sr) * 256 + k0 + sc);
        *(u16x8*)&Bs[sr + 32][sc] = *(const u16x8*)(B + (n0 + sr + 32) * 256 + k0 + sc);
        __syncthreads();
        #pragma unroll
        for (int kk = 0; kk < 64; kk += 32) {
            const bf16x8 a0 = *(const bf16x8*)&As[wy * 32 + lr][kk + lk * 8];
            const bf16x8 a1 = *(const bf16x8*)&As[wy * 32 + 16 + lr][kk + lk * 8];
            const bf16x8 b0 = *(const bf16x8*)&Bs[wx * 32 + lr][kk + lk * 8];
            const bf16x8 b1 = *(const bf16x8*)&Bs[wx * 32 + 16 + lr][kk + lk * 8];
            acc[0][0] = __builtin_amdgcn_mfma_f32_16x16x32_bf16(a0, b0, acc[0][0], 0, 0, 0);
            acc[0][1] = __builtin_amdgcn_mfma_f32_16x16x32_bf16(a0, b1, acc[0][1], 0, 0, 0);
            acc[1][0] = __builtin_amdgcn_mfma_f32_16x16x32_bf16(a1, b0, acc[1][0], 0, 0, 0);
            acc[1][1] = __builtin_amdgcn_mfma_f32_16x16x32_bf16(a1, b1, acc[1][1], 0, 0, 0);
        }
        __syncthreads();
    }

    // epilogue: C/D layout col = lane&15, row = (lane>>4)*4 + reg
    #pragma unroll
    for (int mi = 0; mi < 2; mi++) {
        #pragma unroll
        for (int ni = 0; ni < 2; ni++) {
            #pragma unroll
            for (int r = 0; r < 4; r++) {
                const int row = m0 + wy * 32 + mi * 16 + lk * 4 + r;
                const int col = n0 + wx * 32 + ni * 16 + lr;
                if (left) {
                    Lp[b * 131072 + row * 512 + col] = acc[mi][ni][r] + b_lin[col];
                } else {
                    Rt[b * 131072 + row * 256 + col] = f2bf(acc[mi][ni][r]);
                }
            }
        }
    }
}

// ---------------------------------------------------------------------------
// Kernel 2: score (rank-1 + |p| trick) + softmax + attn@v + sigmoid + T-store
// block = (b, 4-row i-tile); thread = j in score phase, w' in matvec phase.
// e[i][j] = u[i] + racc[j] + sum_e 0.4a_e*|L'[i,e]+R[e,j]| + bias
//   where u[i] = sum_e 0.6a_e*L'[i,e], racc[j] = sum_e 0.6a_e*R[e,j]
// ---------------------------------------------------------------------------
__global__ __launch_bounds__(256) void attn_kernel(
    const float* __restrict__ x,              // (8,256,256)
    const float* __restrict__ Lp,             // (8,256,512) fp32, b_lin folded
    const unsigned short* __restrict__ Rt,    // (8,512,256) bf16
    const float* __restrict__ a,              // (512)
    const float* __restrict__ bias,           // (256,256)
    float* __restrict__ out)                  // (8,256,256)
{
    const int b   = blockIdx.x >> 6;
    const int i0  = (blockIdx.x & 63) * 4;
    const int tid = threadIdx.x;

    __shared__ float Ls[4][512];
    __shared__ float c1s[512];
    __shared__ float c2s[512];
    __shared__ float u_s[4];
    __shared__ float at[4][256];

    const float* LpB = Lp + b * 131072 + i0 * 512;
    #pragma unroll
    for (int idx = tid; idx < 2048; idx += 256)
        Ls[idx >> 9][idx & 511] = LpB[idx];
    #pragma unroll
    for (int idx = tid; idx < 512; idx += 256) {
        const float ae = a[idx];
        c1s[idx] = 0.6f * ae;
        c2s[idx] = 0.4f * ae;
    }
    __syncthreads();

    // u[i] = sum_e c1[e] * Ls[i][e]  — wave i reduces row i
    {
        const int i = tid >> 6, lane = tid & 63;
        float p = 0.f;
        #pragma unroll
        for (int kq = 0; kq < 8; kq++)
            p += c1s[lane + 64 * kq] * Ls[i][lane + 64 * kq];
        #pragma unroll
        for (int off = 32; off; off >>= 1) p += __shfl_xor(p, off);
        if (lane == 0) u_s[i] = p;
    }
    __syncthreads();

    // ---- score phase: thread = j, pipelined bf16 R reads ----
    const unsigned short* Rb = Rt + b * 131072 + tid;
    unsigned int rr[8], nn[8];
    #pragma unroll
    for (int s = 0; s < 8; s++) rr[s] = Rb[s * 256];
    float racc = 0.f;
    float acc2[4] = {0.f, 0.f, 0.f, 0.f};

    for (int e0 = 0; e0 < 512; e0 += 8) {
        if (e0 + 8 < 512) {
            #pragma unroll
            for (int s = 0; s < 8; s++) nn[s] = Rb[(e0 + 8 + s) * 256];
        }
        #pragma unroll
        for (int q = 0; q < 2; q++) {
            const int eb = e0 + q * 4;
            float c1v[4], c2v[4], lv0[4], lv1[4], lv2[4], lv3[4];
            *(float4*)c1v = *(const float4*)&c1s[eb];
            *(float4*)c2v = *(const float4*)&c2s[eb];
            *(float4*)lv0 = *(const float4*)&Ls[0][eb];
            *(float4*)lv1 = *(const float4*)&Ls[1][eb];
            *(float4*)lv2 = *(const float4*)&Ls[2][eb];
            *(float4*)lv3 = *(const float4*)&Ls[3][eb];
            #pragma unroll
            for (int s = 0; s < 4; s++) {
                const float rv = bf2f(rr[q * 4 + s]);
                racc += c1v[s] * rv;
                float p;
                p = lv0[s] + rv; acc2[0] = fmaf(c2v[s], fabsf(p), acc2[0]);
                p = lv1[s] + rv; acc2[1] = fmaf(c2v[s], fabsf(p), acc2[1]);
                p = lv2[s] + rv; acc2[2] = fmaf(c2v[s], fabsf(p), acc2[2]);
                p = lv3[s] + rv; acc2[3] = fmaf(c2v[s], fabsf(p), acc2[3]);
            }
        }
        #pragma unroll
        for (int s = 0; s < 8; s++) rr[s] = nn[s];
    }

    #pragma unroll
    for (int i = 0; i < 4; i++)
        at[i][tid] = u_s[i] + racc + acc2[i] + bias[(i0 + i) * 256 + tid];
    __syncthreads();

    // ---- softmax: wave i handles row i ----
    {
        const int i = tid >> 6, lane = tid & 63;
        float v[4];
        float m = -1e30f;
        #pragma unroll
        for (int u = 0; u < 4; u++) {
            v[u] = at[i][lane + 64 * u];
            m = fmaxf(m, v[u]);
        }
        #pragma unroll
        for (int off = 32; off; off >>= 1) m = fmaxf(m, __shfl_xor(m, off));
        float s = 0.f;
        #pragma unroll
        for (int u = 0; u < 4; u++) { v[u] = __expf(v[u] - m); s += v[u]; }
        #pragma unroll
        for (int off = 32; off; off >>= 1) s += __shfl_xor(s, off);
        const float inv = 1.f / s;
        #pragma unroll
        for (int u = 0; u < 4; u++) at[i][lane + 64 * u] = v[u] * inv;
    }
    __syncthreads();

    // ---- matvec: thread = w'; h[i] = sum_j attn[i][j] * x[b][w'][j] ----
    const float* xrow = x + b * 65536 + tid * 256;
    float h[4] = {0.f, 0.f, 0.f, 0.f};
    for (int j = 0; j < 256; j += 4) {
        const float4 xv = *(const float4*)(xrow + j);
        #pragma unroll
        for (int i = 0; i < 4; i++) {
            const float4 pv = *(const float4*)&at[i][j];
            h[i] += pv.x * xv.x + pv.y * xv.y + pv.z * xv.z + pv.w * xv.w;
        }
    }
    float4 o;
    o.x = 1.f / (1.f + __expf(-h[0]));
    o.y = 1.f / (1.f + __expf(-h[1]));
    o.z = 1.f / (1.f + __expf(-h[2]));
    o.w = 1.f / (1.f + __expf(-h[3]));
    *(float4*)(out + b * 65536 + tid * 256 + i0) = o;
}

extern "C" void kernel_launch(void* const* d_in, const int* in_sizes, int n_in,
                              void* d_out, int out_size, void* d_ws, size_t ws_size,
                              hipStream_t stream) {
    const float* x     = (const float*)d_in[0];
    const float* W     = (const float*)d_in[1];
    const float* b_lin = (const float*)d_in[2];
    const float* a     = (const float*)d_in[3];
    const float* bias  = (const float*)d_in[4];
    float* out = (float*)d_out;

    char* ws = (char*)d_ws;
    float*          Lp = (float*)ws;                          // 4 MB
    unsigned short* Rt = (unsigned short*)(ws + (4 << 20));   // 2 MB
    unsigned short* xT = (unsigned short*)(ws + (6 << 20));   // 1 MB
    unsigned short* Wb = (unsigned short*)(ws + (7 << 20));   // 0.5 MB

    convert_kernel<<<256, 256, 0, stream>>>(x, W, xT, Wb);
    mfma_gemm_kernel<<<dim3(64, 8), 256, 0, stream>>>(xT, Wb, b_lin, Lp, Rt);
    attn_kernel<<<512, 256, 0, stream>>>(x, Lp, Rt, a, bias, out);
}

// Round 3
// 115.432 us; speedup vs baseline: 1.3327x; 1.1211x over previous
//
#include <hip/hip_runtime.h>
#include <math.h>

#define ALPHA 0.2f

typedef float f32x4 __attribute__((ext_vector_type(4)));
typedef __bf16 bf16x8 __attribute__((ext_vector_type(8)));
typedef unsigned short u16x8 __attribute__((ext_vector_type(8)));

__device__ __forceinline__ unsigned short f2bf(float f) {
    union { float f; unsigned int u; } v; v.f = f;
    unsigned int u = v.u;
    return (unsigned short)((u + 0x7fffu + ((u >> 16) & 1u)) >> 16);  // RNE
}
__device__ __forceinline__ float bf2f(unsigned int bits) {
    union { unsigned int u; float f; } v; v.u = bits << 16;
    return v.f;
}
__device__ __forceinline__ float sigmoidf_(float v) {
    return 1.f / (1.f + __expf(-v));
}

// ---------------------------------------------------------------------------
// Kernel 0: convert/pack.
//  blocks [0,128):  xT_bf[b][k][w] = bf16(x[b][w][k])       (8,256,256)
//  blocks [128,256): Wb[e2][w] = bf16(e2<512 ? W[e2][w] : W[e2-512][256+w])
// ---------------------------------------------------------------------------
__global__ __launch_bounds__(256) void convert_kernel(
    const float* __restrict__ x, const float* __restrict__ W,
    unsigned short* __restrict__ xT, unsigned short* __restrict__ Wb)
{
    const int tid = threadIdx.x;
    if (blockIdx.x < 128) {
        const int b  = blockIdx.x >> 4;
        const int tt = blockIdx.x & 15;
        const int k0 = (tt >> 2) * 64;
        const int w0 = (tt & 3) * 64;
        __shared__ float Td[64][68];   // Td[k][w]
        const int wl = tid >> 4;       // 0..15
        const int kg = tid & 15;       // 0..15
        #pragma unroll
        for (int p = 0; p < 4; p++) {
            const int w = wl + 16 * p;
            const float4 v = *(const float4*)(x + b * 65536 + (w0 + w) * 256 + k0 + kg * 4);
            Td[kg * 4 + 0][w] = v.x;
            Td[kg * 4 + 1][w] = v.y;
            Td[kg * 4 + 2][w] = v.z;
            Td[kg * 4 + 3][w] = v.w;
        }
        __syncthreads();
        const int c8 = (tid & 7) * 8;
        #pragma unroll
        for (int p = 0; p < 2; p++) {
            const int rk = (tid >> 3) + 32 * p;
            u16x8 o;
            #pragma unroll
            for (int j = 0; j < 8; j++) o[j] = f2bf(Td[rk][c8 + j]);
            *(u16x8*)(xT + b * 65536 + (k0 + rk) * 256 + w0 + c8) = o;
        }
    } else {
        const int base = (blockIdx.x - 128) * 2048 + tid * 8;
        const int e2 = base >> 8;
        const int w8 = base & 255;
        const float* src = (e2 < 512) ? (W + e2 * 512 + w8)
                                      : (W + (e2 - 512) * 512 + 256 + w8);
        const float4 v0 = *(const float4*)(src);
        const float4 v1 = *(const float4*)(src + 4);
        u16x8 o;
        o[0] = f2bf(v0.x); o[1] = f2bf(v0.y); o[2] = f2bf(v0.z); o[3] = f2bf(v0.w);
        o[4] = f2bf(v1.x); o[5] = f2bf(v1.y); o[6] = f2bf(v1.z); o[7] = f2bf(v1.w);
        *(u16x8*)(Wb + e2 * 256 + w8) = o;
    }
}

// ---------------------------------------------------------------------------
// Kernel 1: MFMA bf16 GEMM, C[m][n] = sum_k A[m][k]*B[n][k], K=256.
//  left  (tiles 0..31):  A=xT[b], B=Wb[0:512]  -> Lp[b][k][e] = C + b_lin[e]
//  right (tiles 32..63): A=Wb[512:], B=xT[b]   -> R4[b][e>>2][j][e&3] = C (fp32 swizzled)
// ---------------------------------------------------------------------------
__global__ __launch_bounds__(256) void mfma_gemm_kernel(
    const unsigned short* __restrict__ xT, const unsigned short* __restrict__ Wb,
    const float* __restrict__ b_lin,
    float* __restrict__ Lp, float* __restrict__ R4)
{
    const int b = blockIdx.y;
    const int t = blockIdx.x;
    const bool left = (t < 32);
    const unsigned short *A, *B;
    int m0, n0;
    if (left) {
        m0 = (t >> 3) * 64; n0 = (t & 7) * 64;
        A = xT + b * 65536; B = Wb;
    } else {
        const int tt = t - 32;
        m0 = (tt >> 2) * 64; n0 = (tt & 3) * 64;
        A = Wb + 512 * 256; B = xT + b * 65536;
    }

    __shared__ unsigned short As[64][72];
    __shared__ unsigned short Bs[64][72];

    const int tid  = threadIdx.x;
    const int wv   = tid >> 6;
    const int lane = tid & 63;
    const int wy = wv >> 1, wx = wv & 1;
    const int lr = lane & 15;
    const int lk = lane >> 4;

    f32x4 acc[2][2];
    #pragma unroll
    for (int i = 0; i < 2; i++)
        #pragma unroll
        for (int j = 0; j < 2; j++) acc[i][j] = (f32x4){0.f, 0.f, 0.f, 0.f};

    const int sr = tid >> 3;           // 0..31
    const int sc = (tid & 7) * 8;      // 0..56

    for (int k0 = 0; k0 < 256; k0 += 64) {
        *(u16x8*)&As[sr][sc]      = *(const u16x8*)(A + (m0 + sr) * 256 + k0 + sc);
        *(u16x8*)&As[sr + 32][sc] = *(const u16x8*)(A + (m0 + sr + 32) * 256 + k0 + sc);
        *(u16x8*)&Bs[sr][sc]      = *(const u16x8*)(B + (n0 + sr) * 256 + k0 + sc);
        *(u16x8*)&Bs[sr + 32][sc] = *(const u16x8*)(B + (n0 + sr + 32) * 256 + k0 + sc);
        __syncthreads();
        #pragma unroll
        for (int kk = 0; kk < 64; kk += 32) {
            const bf16x8 a0 = *(const bf16x8*)&As[wy * 32 + lr][kk + lk * 8];
            const bf16x8 a1 = *(const bf16x8*)&As[wy * 32 + 16 + lr][kk + lk * 8];
            const bf16x8 b0 = *(const bf16x8*)&Bs[wx * 32 + lr][kk + lk * 8];
            const bf16x8 b1 = *(const bf16x8*)&Bs[wx * 32 + 16 + lr][kk + lk * 8];
            acc[0][0] = __builtin_amdgcn_mfma_f32_16x16x32_bf16(a0, b0, acc[0][0], 0, 0, 0);
            acc[0][1] = __builtin_amdgcn_mfma_f32_16x16x32_bf16(a0, b1, acc[0][1], 0, 0, 0);
            acc[1][0] = __builtin_amdgcn_mfma_f32_16x16x32_bf16(a1, b0, acc[1][0], 0, 0, 0);
            acc[1][1] = __builtin_amdgcn_mfma_f32_16x16x32_bf16(a1, b1, acc[1][1], 0, 0, 0);
        }
        __syncthreads();
    }

    // epilogue: C/D layout col = lane&15, row = (lane>>4)*4 + reg
    #pragma unroll
    for (int mi = 0; mi < 2; mi++) {
        #pragma unroll
        for (int ni = 0; ni < 2; ni++) {
            const int row = m0 + wy * 32 + mi * 16 + lk * 4;   // +reg
            const int col = n0 + wx * 32 + ni * 16 + lr;
            if (left) {
                #pragma unroll
                for (int r = 0; r < 4; r++)
                    Lp[b * 131072 + (row + r) * 512 + col] = acc[mi][ni][r] + b_lin[col];
            } else {
                float4 o;
                o.x = acc[mi][ni][0]; o.y = acc[mi][ni][1];
                o.z = acc[mi][ni][2]; o.w = acc[mi][ni][3];
                *(float4*)(R4 + b * 131072 + (row >> 2) * 1024 + col * 4) = o;
            }
        }
    }
}

// ---------------------------------------------------------------------------
// Kernel 2: score (rank-1 + |p|) + softmax + attn@v + sigmoid + T-store
// 512 threads: score phase thread=(j, e-half); matvec thread=(w', j-half).
// e[i][j] = u[i] + racc[j] + sum_e 0.4a_e*|L'[i,e]+R[e,j]| + bias
// ---------------------------------------------------------------------------
__global__ __launch_bounds__(512) void attn_kernel(
    const unsigned short* __restrict__ xT,    // (8,256,256) bf16  xT[b][j][w]
    const float* __restrict__ Lp,             // (8,256,512) fp32, b_lin folded
    const float* __restrict__ R4,             // (8,128,256,4) fp32 swizzled
    const float* __restrict__ a,              // (512)
    const float* __restrict__ bias,           // (256,256)
    float* __restrict__ out)                  // (8,256,256)
{
    const int b   = blockIdx.x >> 6;
    const int i0  = (blockIdx.x & 63) * 4;
    const int tid = threadIdx.x;
    const int j   = tid & 255;
    const int eh  = tid >> 8;                 // e-half: 0 or 1

    __shared__ float buf[4100];
    float* Ls  = buf;                          // [4][512] (score phase)
    float* c1s = buf + 2048;                   // [512]
    float* c2s = buf + 2560;                   // [512]
    float* at  = buf + 3072;                   // [4][256]
    float* u_s = buf + 4096;                   // [4]
    // reused after score: acc2P = buf[0:1024], raccP = buf[1024:1280], hp = buf[0:1024]

    const float* LpB = Lp + b * 131072 + i0 * 512;
    for (int idx = tid; idx < 2048; idx += 512) Ls[idx] = LpB[idx];
    if (tid < 512) {
        const float ae = a[tid];
        c1s[tid] = 0.6f * ae;
        c2s[tid] = 0.4f * ae;
    }
    __syncthreads();

    // u[i] = sum_e c1[e]*L[i][e] — wave i (tid<256) reduces row i
    if (tid < 256) {
        const int i = tid >> 6, lane = tid & 63;
        float p = 0.f;
        #pragma unroll
        for (int q = 0; q < 8; q++)
            p += c1s[lane + 64 * q] * Ls[i * 512 + lane + 64 * q];
        #pragma unroll
        for (int off = 32; off; off >>= 1) p += __shfl_xor(p, off);
        if (lane == 0) u_s[i] = p;
    }

    // ---- score phase: 256 e per thread, float4 R loads (swizzled layout) ----
    const float* Rb = R4 + b * 131072 + eh * 65536 + j * 4;
    const int ebase = eh * 256;
    float racc = 0.f;
    float acc2[4] = {0.f, 0.f, 0.f, 0.f};

    float4 r0 = *(const float4*)(Rb);
    float4 r1 = *(const float4*)(Rb + 1024);
    for (int el = 0; el < 256; el += 8) {
        float4 n0, n1;
        if (el + 8 < 256) {
            n0 = *(const float4*)(Rb + (el + 8) * 256);
            n1 = *(const float4*)(Rb + (el + 8) * 256 + 1024);
        }
        #pragma unroll
        for (int q = 0; q < 2; q++) {
            const float4 rv = q ? r1 : r0;
            const int eb = ebase + el + q * 4;
            const float4 c1v = *(const float4*)&c1s[eb];
            const float4 c2v = *(const float4*)&c2s[eb];
            const float4 l0 = *(const float4*)&Ls[eb];
            const float4 l1 = *(const float4*)&Ls[512 + eb];
            const float4 l2 = *(const float4*)&Ls[1024 + eb];
            const float4 l3 = *(const float4*)&Ls[1536 + eb];
            racc += c1v.x * rv.x + c1v.y * rv.y + c1v.z * rv.z + c1v.w * rv.w;
            float p;
            p = l0.x + rv.x; acc2[0] = fmaf(c2v.x, fabsf(p), acc2[0]);
            p = l0.y + rv.y; acc2[0] = fmaf(c2v.y, fabsf(p), acc2[0]);
            p = l0.z + rv.z; acc2[0] = fmaf(c2v.z, fabsf(p), acc2[0]);
            p = l0.w + rv.w; acc2[0] = fmaf(c2v.w, fabsf(p), acc2[0]);
            p = l1.x + rv.x; acc2[1] = fmaf(c2v.x, fabsf(p), acc2[1]);
            p = l1.y + rv.y; acc2[1] = fmaf(c2v.y, fabsf(p), acc2[1]);
            p = l1.z + rv.z; acc2[1] = fmaf(c2v.z, fabsf(p), acc2[1]);
            p = l1.w + rv.w; acc2[1] = fmaf(c2v.w, fabsf(p), acc2[1]);
            p = l2.x + rv.x; acc2[2] = fmaf(c2v.x, fabsf(p), acc2[2]);
            p = l2.y + rv.y; acc2[2] = fmaf(c2v.y, fabsf(p), acc2[2]);
            p = l2.z + rv.z; acc2[2] = fmaf(c2v.z, fabsf(p), acc2[2]);
            p = l2.w + rv.w; acc2[2] = fmaf(c2v.w, fabsf(p), acc2[2]);
            p = l3.x + rv.x; acc2[3] = fmaf(c2v.x, fabsf(p), acc2[3]);
            p = l3.y + rv.y; acc2[3] = fmaf(c2v.y, fabsf(p), acc2[3]);
            p = l3.z + rv.z; acc2[3] = fmaf(c2v.z, fabsf(p), acc2[3]);
            p = l3.w + rv.w; acc2[3] = fmaf(c2v.w, fabsf(p), acc2[3]);
        }
        r0 = n0; r1 = n1;
    }
    __syncthreads();   // all Ls reads done; buf[0:1280] reusable

    float* acc2P = buf;          // [4][256]
    float* raccP = buf + 1024;   // [256]
    if (eh == 1) {
        #pragma unroll
        for (int i = 0; i < 4; i++) acc2P[i * 256 + j] = acc2[i];
        raccP[j] = racc;
    }
    __syncthreads();
    if (eh == 0) {
        #pragma unroll
        for (int i = 0; i < 4; i++)
            at[i * 256 + j] = u_s[i] + racc + raccP[j] + acc2[i] + acc2P[i * 256 + j]
                            + bias[(i0 + i) * 256 + j];
    }
    __syncthreads();

    // ---- softmax: wave i (tid<256) handles row i ----
    if (tid < 256) {
        const int i = tid >> 6, lane = tid & 63;
        float v[4];
        float m = -1e30f;
        #pragma unroll
        for (int u = 0; u < 4; u++) {
            v[u] = at[i * 256 + lane + 64 * u];
            m = fmaxf(m, v[u]);
        }
        #pragma unroll
        for (int off = 32; off; off >>= 1) m = fmaxf(m, __shfl_xor(m, off));
        float s = 0.f;
        #pragma unroll
        for (int u = 0; u < 4; u++) { v[u] = __expf(v[u] - m); s += v[u]; }
        #pragma unroll
        for (int off = 32; off; off >>= 1) s += __shfl_xor(s, off);
        const float inv = 1.f / s;
        #pragma unroll
        for (int u = 0; u < 4; u++) at[i * 256 + lane + 64 * u] = v[u] * inv;
    }
    __syncthreads();

    // ---- matvec: thread=(w', j-half); h[i] = sum_j attn[i][j]*xT[b][j][w'] ----
    const int wp  = tid & 255;
    const int jh  = tid >> 8;
    const unsigned short* xTb = xT + b * 65536 + jh * 128 * 256 + wp;
    float h[4] = {0.f, 0.f, 0.f, 0.f};
    for (int jj = 0; jj < 128; jj += 4) {
        float xv[4];
        #pragma unroll
        for (int s = 0; s < 4; s++) xv[s] = bf2f(xTb[(jj + s) * 256]);
        const int jg = jh * 128 + jj;
        #pragma unroll
        for (int i = 0; i < 4; i++) {
            const float4 av = *(const float4*)&at[i * 256 + jg];
            h[i] += av.x * xv[0] + av.y * xv[1] + av.z * xv[2] + av.w * xv[3];
        }
    }
    __syncthreads();
    float* hp = buf;             // [4][256]
    if (jh == 1) {
        #pragma unroll
        for (int i = 0; i < 4; i++) hp[i * 256 + wp] = h[i];
    }
    __syncthreads();
    if (jh == 0) {
        float4 o;
        o.x = sigmoidf_(h[0] + hp[0 * 256 + wp]);
        o.y = sigmoidf_(h[1] + hp[1 * 256 + wp]);
        o.z = sigmoidf_(h[2] + hp[2 * 256 + wp]);
        o.w = sigmoidf_(h[3] + hp[3 * 256 + wp]);
        *(float4*)(out + b * 65536 + wp * 256 + i0) = o;
    }
}

extern "C" void kernel_launch(void* const* d_in, const int* in_sizes, int n_in,
                              void* d_out, int out_size, void* d_ws, size_t ws_size,
                              hipStream_t stream) {
    const float* x     = (const float*)d_in[0];
    const float* W     = (const float*)d_in[1];
    const float* b_lin = (const float*)d_in[2];
    const float* a     = (const float*)d_in[3];
    const float* bias  = (const float*)d_in[4];
    float* out = (float*)d_out;

    char* ws = (char*)d_ws;
    float*          Lp = (float*)ws;                          // 4 MB
    float*          R4 = (float*)(ws + (4 << 20));            // 4 MB (fp32 swizzled)
    unsigned short* xT = (unsigned short*)(ws + (8 << 20));   // 1 MB
    unsigned short* Wb = (unsigned short*)(ws + (9 << 20));   // 0.5 MB

    convert_kernel<<<256, 256, 0, stream>>>(x, W, xT, Wb);
    mfma_gemm_kernel<<<dim3(64, 8), 256, 0, stream>>>(xT, Wb, b_lin, Lp, R4);
    attn_kernel<<<512, 512, 0, stream>>>(xT, Lp, R4, a, bias, out);
}